// Round 5
// baseline (228.362 us; speedup 1.0000x reference)
//
#include <hip/hip_runtime.h>
#include <math.h>

typedef _Float16 h2 __attribute__((ext_vector_type(2)));

#define Bsz 16
#define Ssz 1024
#define TOKENS (Bsz * Ssz)   // 16384
#define Dd 64
#define Hh 8
#define KSPLIT 4
#define KCH (Ssz / KSPLIT)   // 256 keys per attn block

#if __has_builtin(__builtin_amdgcn_exp2f)
  #define EXPFN(x) __builtin_amdgcn_exp2f(x)
  #define PRESCALE 0.51007025f          // (1/sqrt(8)) * log2(e)
#else
  #define EXPFN(x) __expf(x)
  #define PRESCALE 0.35355339059f       // 1/sqrt(8)
#endif

__device__ __forceinline__ float fdot2(h2 a, h2 b, float c) {
#if __has_builtin(__builtin_amdgcn_fdot2)
  return __builtin_amdgcn_fdot2(a, b, c, false);
#else
  return fmaf((float)a.x, (float)b.x, fmaf((float)a.y, (float)b.y, c));
#endif
}

__device__ __forceinline__ h2 pkrtz(float a, float b) {
#if __has_builtin(__builtin_amdgcn_cvt_pkrtz)
  return __builtin_bit_cast(h2, __builtin_amdgcn_cvt_pkrtz(a, b));
#else
  h2 r; r.x = (_Float16)a; r.y = (_Float16)b; return r;
#endif
}

__device__ __forceinline__ h2 as_h2(unsigned int u) {
  return __builtin_bit_cast(h2, u);
}
__device__ __forceinline__ unsigned int as_u32(h2 v) {
  return __builtin_bit_cast(unsigned int, v);
}

#if __has_builtin(__builtin_amdgcn_readlane)
__device__ __forceinline__ float rdlane(float v, int l) {
  return __int_as_float(__builtin_amdgcn_readlane(__float_as_int(v), l));
}
#else
__device__ __forceinline__ float rdlane(float v, int l) { return __shfl(v, l, 64); }
#endif

__device__ __forceinline__ float wave_reduce_sum(float v) {
#pragma unroll
  for (int off = 32; off >= 1; off >>= 1) v += __shfl_xor(v, off, 64);
  return v;
}

// quantum head q-vector for one token/head
__device__ __forceinline__ void qheads(const float* __restrict__ xp,
                                       const float* th, float* o) {
  float4 v0 = *(const float4*)(xp);
  float4 v1 = *(const float4*)(xp + 4);
  float c0 = __cosf(v0.x + th[0]), c1 = __cosf(v0.y + th[1]);
  float c2 = __cosf(v0.z + th[2]), c3 = __cosf(v0.w + th[3]);
  float c4 = __cosf(v1.x + th[4]), c5 = __cosf(v1.y + th[5]);
  float c6 = __cosf(v1.z + th[6]), c7 = __cosf(v1.w + th[7]);
  float cp = c0;
  cp *= c1; o[1] = cp; cp *= c2; o[2] = cp; cp *= c3; o[3] = cp;
  cp *= c4; o[4] = cp; cp *= c5; o[5] = cp; cp *= c6; o[6] = cp;
  cp *= c7; o[7] = cp;
  o[0] = c1 * c2 * c3 * c4 * c5 * c6 * c7;
}

// ---------------------------------------------------------------- embed + pos
// 2 elements (one sin/cos pair) per thread, float2 I/O.
__global__ __launch_bounds__(256) void embed_kernel(
    const int* __restrict__ tokens, const float* __restrict__ emb,
    float* __restrict__ x) {
  int gid = blockIdx.x * 256 + threadIdx.x;   // 0 .. TOKENS*32-1
  if (gid >= TOKENS * 32) return;
  int d2 = gid & 31;
  int ts = gid >> 5;
  int s  = ts & (Ssz - 1);
  int tok = tokens[ts];
  float freq = __expf((float)(2 * d2) * (-0.14391156831f));
  float ang = (float)s * freq;
  float sn, cs;
  __sincosf(ang, &sn, &cs);
  float2 e2 = *(const float2*)&emb[(size_t)tok * Dd + 2 * d2];
  float2 r;
  r.x = e2.x + sn;
  r.y = e2.y + cs;
  *(float2*)&x[(size_t)ts * Dd + 2 * d2] = r;
}

// ------------------------------------------------- quantum heads + attention
// grid = 128 bh * 2 rowchunks * 4 ksplit = 1024 blocks, 256 threads.
// fp16 v_dot2_f32_f16 inner loop, 2 keys x 2 rows per iteration.
__global__ __launch_bounds__(256, 4) void attn_kernel(
    const float* __restrict__ x, const float* __restrict__ theta,
    float* __restrict__ apart) {
  __shared__ float qsT[8 * KCH];          // [d][k] fp32 (8 KB)
  __shared__ unsigned int kd[KCH * 4];    // [k][c2]: (q[2c2],q[2c2+1]) f16x2 (4 KB)
  __shared__ unsigned int ka[(KCH / 2) * 8]; // [k2][d]: (q_{2k2}[d],q_{2k2+1}[d]) (4 KB)
  int blk = blockIdx.x;
  int bh  = blk >> 3;
  int sub = blk & 7;
  int rc  = sub >> 2;
  int ks  = sub & 3;
  int b = bh >> 3, h = bh & 7;
  int t = threadIdx.x;

  float th[8];
#pragma unroll
  for (int i = 0; i < 8; i++) th[i] = theta[i];

  const float* xb = x + (size_t)b * Ssz * Dd + h * 8;

  // stage this block's keys: fp32 transposed + f16x2 dot-layout
  {
    float o[8];
    qheads(xb + (size_t)(ks * KCH + t) * Dd, th, o);
#pragma unroll
    for (int d = 0; d < 8; d++) qsT[d * KCH + t] = o[d];
#pragma unroll
    for (int j = 0; j < 4; j++)
      kd[t * 4 + j] = as_u32(pkrtz(o[2 * j], o[2 * j + 1]));
  }

  // this thread's two rows (prescaled, fp16-packed)
  int r0 = rc * 512 + t;
  int r1 = r0 + 256;
  float q0[8], q1[8];
  qheads(xb + (size_t)r0 * Dd, th, q0);
  qheads(xb + (size_t)r1 * Dd, th, q1);
  h2 qp0[4], qp1[4];
#pragma unroll
  for (int j = 0; j < 4; j++) {
    qp0[j] = pkrtz(q0[2 * j] * PRESCALE, q0[2 * j + 1] * PRESCALE);
    qp1[j] = pkrtz(q1[2 * j] * PRESCALE, q1[2 * j + 1] * PRESCALE);
  }
  __syncthreads();

  // build acc-layout: key-pairs per component
  if (t < KCH / 2) {
#pragma unroll
    for (int d = 0; d < 8; d++) {
      float2 v = *(const float2*)&qsT[d * KCH + 2 * t];
      ka[t * 8 + d] = as_u32(pkrtz(v.x, v.y));
    }
  }
  __syncthreads();

  float a0[8], a1[8];
#pragma unroll
  for (int d = 0; d < 8; d++) { a0[d] = 0.f; a1[d] = 0.f; }
  float ps0 = 0.f, ps1 = 0.f;
  const h2 ones = {(_Float16)1.f, (_Float16)1.f};

#pragma unroll 2
  for (int k2 = 0; k2 < KCH / 2; ++k2) {
    uint4 A = *(const uint4*)&kd[(2 * k2) * 4];       // key 2k2
    uint4 B = *(const uint4*)&kd[(2 * k2 + 1) * 4];   // key 2k2+1

    float s00 = fdot2(as_h2(A.w), qp0[3],
                 fdot2(as_h2(A.z), qp0[2],
                  fdot2(as_h2(A.y), qp0[1],
                   fdot2(as_h2(A.x), qp0[0], 0.f))));
    float s01 = fdot2(as_h2(B.w), qp0[3],
                 fdot2(as_h2(B.z), qp0[2],
                  fdot2(as_h2(B.y), qp0[1],
                   fdot2(as_h2(B.x), qp0[0], 0.f))));
    float s10 = fdot2(as_h2(A.w), qp1[3],
                 fdot2(as_h2(A.z), qp1[2],
                  fdot2(as_h2(A.y), qp1[1],
                   fdot2(as_h2(A.x), qp1[0], 0.f))));
    float s11 = fdot2(as_h2(B.w), qp1[3],
                 fdot2(as_h2(B.z), qp1[2],
                  fdot2(as_h2(B.y), qp1[1],
                   fdot2(as_h2(B.x), qp1[0], 0.f))));

    float e00 = EXPFN(s00), e01 = EXPFN(s01);
    float e10 = EXPFN(s10), e11 = EXPFN(s11);
    h2 pe0 = pkrtz(e00, e01);
    h2 pe1 = pkrtz(e10, e11);

    uint4 Ka = *(const uint4*)&ka[k2 * 8];
    uint4 Kb = *(const uint4*)&ka[k2 * 8 + 4];
    a0[0] = fdot2(pe0, as_h2(Ka.x), a0[0]);
    a0[1] = fdot2(pe0, as_h2(Ka.y), a0[1]);
    a0[2] = fdot2(pe0, as_h2(Ka.z), a0[2]);
    a0[3] = fdot2(pe0, as_h2(Ka.w), a0[3]);
    a0[4] = fdot2(pe0, as_h2(Kb.x), a0[4]);
    a0[5] = fdot2(pe0, as_h2(Kb.y), a0[5]);
    a0[6] = fdot2(pe0, as_h2(Kb.z), a0[6]);
    a0[7] = fdot2(pe0, as_h2(Kb.w), a0[7]);
    a1[0] = fdot2(pe1, as_h2(Ka.x), a1[0]);
    a1[1] = fdot2(pe1, as_h2(Ka.y), a1[1]);
    a1[2] = fdot2(pe1, as_h2(Ka.z), a1[2]);
    a1[3] = fdot2(pe1, as_h2(Ka.w), a1[3]);
    a1[4] = fdot2(pe1, as_h2(Kb.x), a1[4]);
    a1[5] = fdot2(pe1, as_h2(Kb.y), a1[5]);
    a1[6] = fdot2(pe1, as_h2(Kb.z), a1[6]);
    a1[7] = fdot2(pe1, as_h2(Kb.w), a1[7]);
    ps0 = fdot2(pe0, ones, ps0);
    ps1 = fdot2(pe1, ones, ps1);
  }

  // partial layout: apart[(bh*4+ks)*9216 + c*1024 + row], c=0..7 acc, c=8 psum
  size_t base = ((size_t)(bh * KSPLIT + ks)) * 9216;
#pragma unroll
  for (int d = 0; d < 8; d++) {
    apart[base + d * 1024 + r0] = a0[d];
    apart[base + d * 1024 + r1] = a1[d];
  }
  apart[base + 8192 + r0] = ps0;
  apart[base + 8192 + r1] = ps1;
}

// ---- tail1: ksplit-combine + normalize + combine-matvec + residual + LN1
__global__ __launch_bounds__(256) void tail1_kernel(
    float* __restrict__ x, const float* __restrict__ apart,
    const float* __restrict__ Wc,
    const float* __restrict__ g1, const float* __restrict__ bb1) {
  int lane = threadIdx.x & 63, w = threadIdx.x >> 6;
  int h = lane >> 3, c = lane & 7;
  float wc[64];
#pragma unroll
  for (int i = 0; i < 16; i++) {
    float4 v = *(const float4*)&Wc[lane * 64 + i * 4];
    wc[4 * i] = v.x; wc[4 * i + 1] = v.y; wc[4 * i + 2] = v.z; wc[4 * i + 3] = v.w;
  }
  float g = g1[lane], bb = bb1[lane];
  int tok0 = blockIdx.x * 16 + w * 4;
  int b = tok0 >> 10;
  size_t hb = ((size_t)(b * 8 + h)) * 4 * 9216 + c * 1024;
  size_t pb = ((size_t)(b * 8 + h)) * 4 * 9216 + 8192;
  for (int it = 0; it < 4; ++it) {
    int tok = tok0 + it;
    int row = tok & 1023;
    // k-split reduction + softmax normalization for this lane's (h,c)
    float pv = apart[hb + row] + apart[hb + 9216 + row] +
               apart[hb + 2 * 9216 + row] + apart[hb + 3 * 9216 + row];
    float psv = apart[pb + row] + apart[pb + 9216 + row] +
                apart[pb + 2 * 9216 + row] + apart[pb + 3 * 9216 + row];
    float av = pv * (1.0f / psv);
    size_t base = (size_t)tok * Dd + lane;
    float xd = x[base];
    float y0 = 0.f, y1 = 0.f, y2 = 0.f, y3 = 0.f;
#pragma unroll
    for (int k = 0; k < 64; k += 4) {
      y0 = fmaf(rdlane(av, k),     wc[k],     y0);
      y1 = fmaf(rdlane(av, k + 1), wc[k + 1], y1);
      y2 = fmaf(rdlane(av, k + 2), wc[k + 2], y2);
      y3 = fmaf(rdlane(av, k + 3), wc[k + 3], y3);
    }
    float r = xd + ((y0 + y1) + (y2 + y3));
    float mu = wave_reduce_sum(r) * (1.f / 64.f);
    float tt = r - mu;
    float var = wave_reduce_sum(tt * tt) * (1.f / 64.f);
    x[base] = tt * rsqrtf(var + 1e-5f) * g + bb;
  }
}

// ------------------- tail2: quantum FFN + residual + LN2 (in-place), pooling
__global__ __launch_bounds__(256) void tail2_kernel(
    float* __restrict__ x,
    const float* __restrict__ g2, const float* __restrict__ bb2,
    const float* __restrict__ fth,
    const float* __restrict__ W1, const float* __restrict__ fb1,
    const float* __restrict__ W2, const float* __restrict__ fb2,
    float* __restrict__ partial, int do_partial) {
  __shared__ float red[4][64];
  int lane = threadIdx.x & 63, w = threadIdx.x >> 6;
  float w2[128];
#pragma unroll
  for (int i = 0; i < 32; i++) {
    float4 v = *(const float4*)&W2[lane * 128 + i * 4];
    w2[4 * i] = v.x; w2[4 * i + 1] = v.y; w2[4 * i + 2] = v.z; w2[4 * i + 3] = v.w;
  }
  float w1a[8], w1b[8];
#pragma unroll
  for (int i = 0; i < 8; i++) {
    w1a[i] = W1[lane * 8 + i];
    w1b[i] = W1[(lane + 64) * 8 + i];
  }
  float fb1a = fb1[lane], fb1b = fb1[lane + 64];
  float g = g2[lane], bb = bb2[lane];
  float fb2d = fb2[lane];
  float cth[8];
#pragma unroll
  for (int i = 0; i < 8; i++) cth[i] = __cosf(fth[i]);

  float pool = 0.f;
  int tok0 = blockIdx.x * 16 + w * 4;
  for (int it = 0; it < 4; ++it) {
    size_t base = (size_t)(tok0 + it) * Dd + lane;
    float x1 = x[base];
    float z[8];
#pragma unroll
    for (int i = 0; i < 8; i++) z[i] = __cosf(rdlane(x1, i)) * cth[i];
    float ha = fb1a, hb = fb1b;
#pragma unroll
    for (int i = 0; i < 8; i++) { ha = fmaf(z[i], w1a[i], ha); hb = fmaf(z[i], w1b[i], hb); }
    ha = fmaxf(ha, 0.f); hb = fmaxf(hb, 0.f);
    float f0 = 0.f, f1 = 0.f, f2 = 0.f, f3 = 0.f;
#pragma unroll
    for (int j = 0; j < 64; j += 4) {
      f0 = fmaf(rdlane(ha, j),     w2[j],     f0);
      f1 = fmaf(rdlane(ha, j + 1), w2[j + 1], f1);
      f2 = fmaf(rdlane(ha, j + 2), w2[j + 2], f2);
      f3 = fmaf(rdlane(ha, j + 3), w2[j + 3], f3);
    }
#pragma unroll
    for (int j = 0; j < 64; j += 4) {
      f0 = fmaf(rdlane(hb, j),     w2[64 + j],     f0);
      f1 = fmaf(rdlane(hb, j + 1), w2[64 + j + 1], f1);
      f2 = fmaf(rdlane(hb, j + 2), w2[64 + j + 2], f2);
      f3 = fmaf(rdlane(hb, j + 3), w2[64 + j + 3], f3);
    }
    float f = fb2d + ((f0 + f1) + (f2 + f3));
    float r2 = x1 + f;
    float mu2 = wave_reduce_sum(r2) * (1.f / 64.f);
    float t2 = r2 - mu2;
    float var2 = wave_reduce_sum(t2 * t2) * (1.f / 64.f);
    float xo = t2 * rsqrtf(var2 + 1e-5f) * g + bb;
    x[base] = xo;
    pool += xo;
  }
  if (do_partial) {
    red[w][lane] = pool;
    __syncthreads();
    if (w == 0) {
      float s = red[0][lane] + red[1][lane] + red[2][lane] + red[3][lane];
      partial[(size_t)blockIdx.x * 64 + lane] = s;
    }
  }
}

// ------------------------------------------------ pooled mean + MLP head
__global__ __launch_bounds__(128) void head_kernel(
    const float* __restrict__ partial,   // [1024][64]
    const float* eW1, const float* eb1, const float* eW2, const float* eb2,
    const float* eW3, const float* eb3, const float* dW1, const float* db1v,
    const float* dW2, const float* db2v, const float* dW3, const float* db3v,
    const float* cW, const float* cb, float* __restrict__ out) {
  __shared__ float bufP[64];
  __shared__ float bufA[128];
  __shared__ float bufB[128];
  int b = blockIdx.x, t = threadIdx.x;
  if (t < 64) {
    float s = 0.f;
    for (int c = 0; c < 64; ++c) s += partial[(size_t)(b * 64 + c) * 64 + t];
    bufP[t] = s * (1.f / 1024.f);
  }
  __syncthreads();
  {
    float v = eb1[t];
    for (int d = 0; d < 64; d++) v = fmaf(bufP[d], eW1[t * 64 + d], v);
    bufA[t] = fmaxf(v, 0.f);
  }
  __syncthreads();
  if (t < 64) {
    float v = eb2[t];
    for (int j = 0; j < 128; j++) v = fmaf(bufA[j], eW2[t * 128 + j], v);
    bufB[t] = fmaxf(v, 0.f);
  }
  __syncthreads();
  if (t < 32) {
    float v = eb3[t];
    for (int d = 0; d < 64; d++) v = fmaf(bufB[d], eW3[t * 64 + d], v);
    bufA[t] = v;   // latent in bufA[0..31]
  }
  __syncthreads();
  if (t < 64) {
    float v = db1v[t];
    for (int k = 0; k < 32; k++) v = fmaf(bufA[k], dW1[t * 32 + k], v);
    bufB[t] = fmaxf(v, 0.f);
  }
  __syncthreads();
  {
    float v = db2v[t];
    for (int k = 0; k < 64; k++) v = fmaf(bufB[k], dW2[t * 64 + k], v);
    bufA[t] = fmaxf(v, 0.f);
  }
  __syncthreads();
  if (t < 64) {
    float v = db3v[t];
    for (int j = 0; j < 128; j++) v = fmaf(bufA[j], dW3[t * 128 + j], v);
    bufB[t] = v;
  }
  __syncthreads();
  if (t < 10) {
    float v = cb[t];
    for (int d = 0; d < 64; d++) v = fmaf(bufB[d], cW[t * 64 + d], v);
    out[b * 10 + t] = v;
  }
}

extern "C" void kernel_launch(void* const* d_in, const int* in_sizes, int n_in,
                              void* d_out, int out_size, void* d_ws, size_t ws_size,
                              hipStream_t stream) {
  const int*   tokens     = (const int*)d_in[0];
  const float* emb        = (const float*)d_in[1];
  const float* attn_theta = (const float*)d_in[2];
  const float* combine_W  = (const float*)d_in[3];
  const float* ln1_g      = (const float*)d_in[4];
  const float* ln1_b      = (const float*)d_in[5];
  const float* ln2_g      = (const float*)d_in[6];
  const float* ln2_b      = (const float*)d_in[7];
  const float* ffn_theta  = (const float*)d_in[8];
  const float* ffn_W1     = (const float*)d_in[9];
  const float* ffn_b1     = (const float*)d_in[10];
  const float* ffn_W2     = (const float*)d_in[11];
  const float* ffn_b2     = (const float*)d_in[12];
  const float* enc_W1 = (const float*)d_in[13]; const float* enc_b1 = (const float*)d_in[14];
  const float* enc_W2 = (const float*)d_in[15]; const float* enc_b2 = (const float*)d_in[16];
  const float* enc_W3 = (const float*)d_in[17]; const float* enc_b3 = (const float*)d_in[18];
  const float* dec_W1 = (const float*)d_in[19]; const float* dec_b1 = (const float*)d_in[20];
  const float* dec_W2 = (const float*)d_in[21]; const float* dec_b2 = (const float*)d_in[22];
  const float* dec_W3 = (const float*)d_in[23]; const float* dec_b3 = (const float*)d_in[24];
  const float* cls_W  = (const float*)d_in[25]; const float* cls_b  = (const float*)d_in[26];

  float* x       = (float*)d_ws;                          // 1M floats
  float* apart   = x + (size_t)TOKENS * 64;               // 128*4*9*1024 floats
  float* partial = apart + (size_t)128 * KSPLIT * 9 * 1024;  // 1024*64 floats
  float* out     = (float*)d_out;

  embed_kernel<<<(TOKENS * 32 + 255) / 256, 256, 0, stream>>>(tokens, emb, x);
  for (int l = 0; l < 2; ++l) {
    attn_kernel<<<128 * 2 * KSPLIT, 256, 0, stream>>>(x, attn_theta + l * 8, apart);
    tail1_kernel<<<TOKENS / 16, 256, 0, stream>>>(
        x, apart, combine_W + l * 4096, ln1_g + l * 64, ln1_b + l * 64);
    tail2_kernel<<<TOKENS / 16, 256, 0, stream>>>(
        x, ln2_g + l * 64, ln2_b + l * 64,
        ffn_theta + l * 8, ffn_W1 + l * 1024, ffn_b1 + l * 128,
        ffn_W2 + l * 8192, ffn_b2 + l * 64, partial, (l == 1) ? 1 : 0);
  }
  head_kernel<<<16, 128, 0, stream>>>(partial, enc_W1, enc_b1, enc_W2, enc_b2,
                                      enc_W3, enc_b3, dec_W1, dec_b1, dec_W2,
                                      dec_b2, dec_W3, dec_b3, cls_W, cls_b, out);
}

// Round 6
// 148.887 us; speedup vs baseline: 1.5338x; 1.5338x over previous
//
#include <hip/hip_runtime.h>
#include <math.h>

typedef _Float16 h2 __attribute__((ext_vector_type(2)));
typedef __fp16 hh4 __attribute__((ext_vector_type(4)));
typedef float f4 __attribute__((ext_vector_type(4)));

#define Bsz 16
#define Ssz 1024
#define TOKENS (Bsz * Ssz)   // 16384
#define Dd 64
#define Hh 8

#if __has_builtin(__builtin_amdgcn_exp2f)
  #define EXPFN(x) __builtin_amdgcn_exp2f(x)
  #define SQRT_PRESCALE 0.7141921f     // sqrt((1/sqrt(8)) * log2(e))
#else
  #define EXPFN(x) __expf(x)
  #define SQRT_PRESCALE 0.5946036f     // sqrt(1/sqrt(8))
#endif

#if __has_builtin(__builtin_amdgcn_mfma_f32_16x16x16_f16)
  #define MFMA16(a, b, c) __builtin_amdgcn_mfma_f32_16x16x16_f16(a, b, c, 0, 0, 0)
#else
  #define MFMA16(a, b, c) __builtin_amdgcn_mfma_f32_16x16x16f16(a, b, c, 0, 0, 0)
#endif

__device__ __forceinline__ h2 pkrtz(float a, float b) {
#if __has_builtin(__builtin_amdgcn_cvt_pkrtz)
  return __builtin_bit_cast(h2, __builtin_amdgcn_cvt_pkrtz(a, b));
#else
  h2 r; r.x = (_Float16)a; r.y = (_Float16)b; return r;
#endif
}
__device__ __forceinline__ unsigned int as_u32(h2 v) {
  return __builtin_bit_cast(unsigned int, v);
}
__device__ __forceinline__ hh4 bc4(uint2 u) {
  return __builtin_bit_cast(hh4, u);
}

#if __has_builtin(__builtin_amdgcn_readlane)
__device__ __forceinline__ float rdlane(float v, int l) {
  return __int_as_float(__builtin_amdgcn_readlane(__float_as_int(v), l));
}
#else
__device__ __forceinline__ float rdlane(float v, int l) { return __shfl(v, l, 64); }
#endif

__device__ __forceinline__ float wave_reduce_sum(float v) {
#pragma unroll
  for (int off = 32; off >= 1; off >>= 1) v += __shfl_xor(v, off, 64);
  return v;
}

// quantum head q-vector for one token/head
__device__ __forceinline__ void qheads(const float* __restrict__ xp,
                                       const float* th, float* o) {
  float4 v0 = *(const float4*)(xp);
  float4 v1 = *(const float4*)(xp + 4);
  float c0 = __cosf(v0.x + th[0]), c1 = __cosf(v0.y + th[1]);
  float c2 = __cosf(v0.z + th[2]), c3 = __cosf(v0.w + th[3]);
  float c4 = __cosf(v1.x + th[4]), c5 = __cosf(v1.y + th[5]);
  float c6 = __cosf(v1.z + th[6]), c7 = __cosf(v1.w + th[7]);
  float cp = c0;
  cp *= c1; o[1] = cp; cp *= c2; o[2] = cp; cp *= c3; o[3] = cp;
  cp *= c4; o[4] = cp; cp *= c5; o[5] = cp; cp *= c6; o[6] = cp;
  cp *= c7; o[7] = cp;
  o[0] = c1 * c2 * c3 * c4 * c5 * c6 * c7;
}

// ---------------------------------------------------------------- embed + pos
__global__ __launch_bounds__(256) void embed_kernel(
    const int* __restrict__ tokens, const float* __restrict__ emb,
    float* __restrict__ x) {
  int gid = blockIdx.x * 256 + threadIdx.x;   // 0 .. TOKENS*32-1
  if (gid >= TOKENS * 32) return;
  int d2 = gid & 31;
  int ts = gid >> 5;
  int s  = ts & (Ssz - 1);
  int tok = tokens[ts];
  float freq = __expf((float)(2 * d2) * (-0.14391156831f));
  float ang = (float)s * freq;
  float sn, cs;
  __sincosf(ang, &sn, &cs);
  float2 e2 = *(const float2*)&emb[(size_t)tok * Dd + 2 * d2];
  float2 r;
  r.x = e2.x + sn;
  r.y = e2.y + cs;
  *(float2*)&x[(size_t)ts * Dd + 2 * d2] = r;
}

// ------------------------------------------------- MFMA flash attention
// grid = 128 bh * 8 rowsplits = 1024 blocks, 256 threads (4 waves).
// Each block: stage all 1024 keys of its (b,h) in LDS (f16), then each wave
// computes 2 row-tiles (16 rows each) against all 64 key-tiles.
// S^T tile = mfma(A=keys, B=rows); exp2; O^T tile += mfma(A=Q^T, B=P^T).
__global__ __launch_bounds__(256, 3) void attn_kernel(
    const float* __restrict__ x, const float* __restrict__ theta,
    float* __restrict__ o_out, float* __restrict__ ps_out) {
  __shared__ unsigned int qrs[Ssz * 4];     // [k][4]: f16x2 dims (2j,2j+1), x sqrt(scale). 16 KB
  __shared__ unsigned int qtt[16 * 514];    // [d][514 u32]: pairs (k,k+1) along k, unscaled. 32.9 KB
  int blk = blockIdx.x;
  int bh = blk >> 3, split = blk & 7;
  int b = bh >> 3, h = bh & 7;
  int t = threadIdx.x;

  float th[8];
#pragma unroll
  for (int i = 0; i < 8; i++) th[i] = theta[i];

  const float* xb = x + (size_t)b * Ssz * Dd + h * 8;

  // stage 4 consecutive rows per thread
#pragma unroll
  for (int i = 0; i < 4; i += 2) {
    int k0 = t * 4 + i;
    float oa[8], ob[8];
    qheads(xb + (size_t)k0 * Dd, th, oa);
    qheads(xb + (size_t)(k0 + 1) * Dd, th, ob);
    uint4 wa, wb;
    wa.x = as_u32(pkrtz(oa[0] * SQRT_PRESCALE, oa[1] * SQRT_PRESCALE));
    wa.y = as_u32(pkrtz(oa[2] * SQRT_PRESCALE, oa[3] * SQRT_PRESCALE));
    wa.z = as_u32(pkrtz(oa[4] * SQRT_PRESCALE, oa[5] * SQRT_PRESCALE));
    wa.w = as_u32(pkrtz(oa[6] * SQRT_PRESCALE, oa[7] * SQRT_PRESCALE));
    wb.x = as_u32(pkrtz(ob[0] * SQRT_PRESCALE, ob[1] * SQRT_PRESCALE));
    wb.y = as_u32(pkrtz(ob[2] * SQRT_PRESCALE, ob[3] * SQRT_PRESCALE));
    wb.z = as_u32(pkrtz(ob[4] * SQRT_PRESCALE, ob[5] * SQRT_PRESCALE));
    wb.w = as_u32(pkrtz(ob[6] * SQRT_PRESCALE, ob[7] * SQRT_PRESCALE));
    *(uint4*)&qrs[k0 * 4] = wa;
    *(uint4*)&qrs[(k0 + 1) * 4] = wb;
#pragma unroll
    for (int d = 0; d < 8; d++)
      qtt[d * 514 + (k0 >> 1)] = as_u32(pkrtz(oa[d], ob[d]));  // unscaled
  }
  // zero d-rows 8..15 of qtt (A rows beyond real dims must be 0)
  for (int j = 8 * 514 + t; j < 16 * 514; j += 256) qtt[j] = 0;
  __syncthreads();

  int l = t & 63, w = t >> 6;
  int g = l >> 4, rr = l & 15;
  int rt0 = split * 8 + w * 2;          // this wave's two row-tiles
  int rowA = rt0 * 16 + rr;
  int rowB = rowA + 16;
  uint2 z2; z2.x = 0; z2.y = 0;
  uint2 buA = (g < 2) ? *(const uint2*)&qrs[rowA * 4 + 2 * g] : z2;
  uint2 buB = (g < 2) ? *(const uint2*)&qrs[rowB * 4 + 2 * g] : z2;
  hh4 BrA = bc4(buA), BrB = bc4(buB);
  f4 zf = {0.f, 0.f, 0.f, 0.f};
  f4 accA = zf, accB = zf;
  float psA = 0.f, psB = 0.f;

#pragma unroll 2
  for (int kt = 0; kt < 64; ++kt) {
    uint2 au = (g < 2) ? *(const uint2*)&qrs[(kt * 16 + rr) * 4 + 2 * g] : z2;
    hh4 Ak = bc4(au);
    f4 sA = MFMA16(Ak, BrA, zf);     // S^T tile: [key 4g+reg][row rr]
    f4 sB = MFMA16(Ak, BrB, zf);
    float pA0 = EXPFN(sA.x), pA1 = EXPFN(sA.y), pA2 = EXPFN(sA.z), pA3 = EXPFN(sA.w);
    float pB0 = EXPFN(sB.x), pB1 = EXPFN(sB.y), pB2 = EXPFN(sB.z), pB3 = EXPFN(sB.w);
    psA += (pA0 + pA1) + (pA2 + pA3);
    psB += (pB0 + pB1) + (pB2 + pB3);
    uint2 pbA, pbB;
    pbA.x = as_u32(pkrtz(pA0, pA1)); pbA.y = as_u32(pkrtz(pA2, pA3));
    pbB.x = as_u32(pkrtz(pB0, pB1)); pbB.y = as_u32(pkrtz(pB2, pB3));
    uint2 qt = *(const uint2*)&qtt[rr * 514 + kt * 8 + 2 * g];  // Q^T[d=rr][keys kt*16+4g..+3]
    hh4 Aq = bc4(qt);
    accA = MFMA16(Aq, bc4(pbA), accA);   // O^T += Q^T · P^T
    accB = MFMA16(Aq, bc4(pbB), accB);
  }
  psA += __shfl_xor(psA, 16, 64); psA += __shfl_xor(psA, 32, 64);
  psB += __shfl_xor(psB, 16, 64); psB += __shfl_xor(psB, 32, 64);

  size_t tokA = (size_t)b * Ssz + rowA;
  size_t tokB = (size_t)b * Ssz + rowB;
  if (g < 2) {   // lanes 0..31 hold valid d = 4g+reg
    *(f4*)&o_out[tokA * 64 + h * 8 + 4 * g] = accA;
    *(f4*)&o_out[tokB * 64 + h * 8 + 4 * g] = accB;
  }
  if (l < 16) {
    ps_out[tokA * 8 + h] = psA;
    ps_out[tokB * 8 + h] = psB;
  }
}

// ---- tail1: normalize + combine-matvec + residual + LN1 (in-place on x)
__global__ __launch_bounds__(256) void tail1_kernel(
    float* __restrict__ x, const float* __restrict__ o_out,
    const float* __restrict__ ps_out, const float* __restrict__ Wc,
    const float* __restrict__ g1, const float* __restrict__ bb1) {
  int lane = threadIdx.x & 63, w = threadIdx.x >> 6;
  float wc[64];
#pragma unroll
  for (int i = 0; i < 16; i++) {
    float4 v = *(const float4*)&Wc[lane * 64 + i * 4];
    wc[4 * i] = v.x; wc[4 * i + 1] = v.y; wc[4 * i + 2] = v.z; wc[4 * i + 3] = v.w;
  }
  float g = g1[lane], bb = bb1[lane];
  int tok0 = blockIdx.x * 16 + w * 4;
  for (int it = 0; it < 4; ++it) {
    int tok = tok0 + it;
    size_t base = (size_t)tok * Dd + lane;
    float xd = x[base];
    float ov = o_out[base];                              // coalesced
    float psv = ps_out[(size_t)tok * 8 + (lane >> 3)];   // 8-lane broadcast
    float av = ov * (1.0f / psv);
    float y0 = 0.f, y1 = 0.f, y2 = 0.f, y3 = 0.f;
#pragma unroll
    for (int k = 0; k < 64; k += 4) {
      y0 = fmaf(rdlane(av, k),     wc[k],     y0);
      y1 = fmaf(rdlane(av, k + 1), wc[k + 1], y1);
      y2 = fmaf(rdlane(av, k + 2), wc[k + 2], y2);
      y3 = fmaf(rdlane(av, k + 3), wc[k + 3], y3);
    }
    float r = xd + ((y0 + y1) + (y2 + y3));
    float mu = wave_reduce_sum(r) * (1.f / 64.f);
    float tt = r - mu;
    float var = wave_reduce_sum(tt * tt) * (1.f / 64.f);
    x[base] = tt * rsqrtf(var + 1e-5f) * g + bb;
  }
}

// ------------------- tail2: quantum FFN + residual + LN2 (in-place), pooling
__global__ __launch_bounds__(256) void tail2_kernel(
    float* __restrict__ x,
    const float* __restrict__ g2, const float* __restrict__ bb2,
    const float* __restrict__ fth,
    const float* __restrict__ W1, const float* __restrict__ fb1,
    const float* __restrict__ W2, const float* __restrict__ fb2,
    float* __restrict__ partial, int do_partial) {
  __shared__ float red[4][64];
  int lane = threadIdx.x & 63, w = threadIdx.x >> 6;
  float w2[128];
#pragma unroll
  for (int i = 0; i < 32; i++) {
    float4 v = *(const float4*)&W2[lane * 128 + i * 4];
    w2[4 * i] = v.x; w2[4 * i + 1] = v.y; w2[4 * i + 2] = v.z; w2[4 * i + 3] = v.w;
  }
  float w1a[8], w1b[8];
#pragma unroll
  for (int i = 0; i < 8; i++) {
    w1a[i] = W1[lane * 8 + i];
    w1b[i] = W1[(lane + 64) * 8 + i];
  }
  float fb1a = fb1[lane], fb1b = fb1[lane + 64];
  float g = g2[lane], bb = bb2[lane];
  float fb2d = fb2[lane];
  float cth[8];
#pragma unroll
  for (int i = 0; i < 8; i++) cth[i] = __cosf(fth[i]);

  float pool = 0.f;
  int tok0 = blockIdx.x * 16 + w * 4;
  for (int it = 0; it < 4; ++it) {
    size_t base = (size_t)(tok0 + it) * Dd + lane;
    float x1 = x[base];
    float z[8];
#pragma unroll
    for (int i = 0; i < 8; i++) z[i] = __cosf(rdlane(x1, i)) * cth[i];
    float ha = fb1a, hb = fb1b;
#pragma unroll
    for (int i = 0; i < 8; i++) { ha = fmaf(z[i], w1a[i], ha); hb = fmaf(z[i], w1b[i], hb); }
    ha = fmaxf(ha, 0.f); hb = fmaxf(hb, 0.f);
    float f0 = 0.f, f1 = 0.f, f2 = 0.f, f3 = 0.f;
#pragma unroll
    for (int j = 0; j < 64; j += 4) {
      f0 = fmaf(rdlane(ha, j),     w2[j],     f0);
      f1 = fmaf(rdlane(ha, j + 1), w2[j + 1], f1);
      f2 = fmaf(rdlane(ha, j + 2), w2[j + 2], f2);
      f3 = fmaf(rdlane(ha, j + 3), w2[j + 3], f3);
    }
#pragma unroll
    for (int j = 0; j < 64; j += 4) {
      f0 = fmaf(rdlane(hb, j),     w2[64 + j],     f0);
      f1 = fmaf(rdlane(hb, j + 1), w2[64 + j + 1], f1);
      f2 = fmaf(rdlane(hb, j + 2), w2[64 + j + 2], f2);
      f3 = fmaf(rdlane(hb, j + 3), w2[64 + j + 3], f3);
    }
    float f = fb2d + ((f0 + f1) + (f2 + f3));
    float r2 = x1 + f;
    float mu2 = wave_reduce_sum(r2) * (1.f / 64.f);
    float t2 = r2 - mu2;
    float var2 = wave_reduce_sum(t2 * t2) * (1.f / 64.f);
    float xo = t2 * rsqrtf(var2 + 1e-5f) * g + bb;
    x[base] = xo;
    pool += xo;
  }
  if (do_partial) {
    red[w][lane] = pool;
    __syncthreads();
    if (w == 0) {
      float s = red[0][lane] + red[1][lane] + red[2][lane] + red[3][lane];
      partial[(size_t)blockIdx.x * 64 + lane] = s;
    }
  }
}

// ------------------------------------------------ pooled mean + MLP head
__global__ __launch_bounds__(128) void head_kernel(
    const float* __restrict__ partial,   // [1024][64]
    const float* eW1, const float* eb1, const float* eW2, const float* eb2,
    const float* eW3, const float* eb3, const float* dW1, const float* db1v,
    const float* dW2, const float* db2v, const float* dW3, const float* db3v,
    const float* cW, const float* cb, float* __restrict__ out) {
  __shared__ float bufP[64];
  __shared__ float bufA[128];
  __shared__ float bufB[128];
  int b = blockIdx.x, t = threadIdx.x;
  if (t < 64) {
    float s = 0.f;
    for (int c = 0; c < 64; ++c) s += partial[(size_t)(b * 64 + c) * 64 + t];
    bufP[t] = s * (1.f / 1024.f);
  }
  __syncthreads();
  {
    float v = eb1[t];
    for (int d = 0; d < 64; d++) v = fmaf(bufP[d], eW1[t * 64 + d], v);
    bufA[t] = fmaxf(v, 0.f);
  }
  __syncthreads();
  if (t < 64) {
    float v = eb2[t];
    for (int j = 0; j < 128; j++) v = fmaf(bufA[j], eW2[t * 128 + j], v);
    bufB[t] = fmaxf(v, 0.f);
  }
  __syncthreads();
  if (t < 32) {
    float v = eb3[t];
    for (int d = 0; d < 64; d++) v = fmaf(bufB[d], eW3[t * 64 + d], v);
    bufA[t] = v;   // latent in bufA[0..31]
  }
  __syncthreads();
  if (t < 64) {
    float v = db1v[t];
    for (int k = 0; k < 32; k++) v = fmaf(bufA[k], dW1[t * 32 + k], v);
    bufB[t] = fmaxf(v, 0.f);
  }
  __syncthreads();
  {
    float v = db2v[t];
    for (int k = 0; k < 64; k++) v = fmaf(bufB[k], dW2[t * 64 + k], v);
    bufA[t] = fmaxf(v, 0.f);
  }
  __syncthreads();
  if (t < 64) {
    float v = db3v[t];
    for (int j = 0; j < 128; j++) v = fmaf(bufA[j], dW3[t * 128 + j], v);
    bufB[t] = v;
  }
  __syncthreads();
  if (t < 10) {
    float v = cb[t];
    for (int d = 0; d < 64; d++) v = fmaf(bufB[d], cW[t * 64 + d], v);
    out[b * 10 + t] = v;
  }
}

extern "C" void kernel_launch(void* const* d_in, const int* in_sizes, int n_in,
                              void* d_out, int out_size, void* d_ws, size_t ws_size,
                              hipStream_t stream) {
  const int*   tokens     = (const int*)d_in[0];
  const float* emb        = (const float*)d_in[1];
  const float* attn_theta = (const float*)d_in[2];
  const float* combine_W  = (const float*)d_in[3];
  const float* ln1_g      = (const float*)d_in[4];
  const float* ln1_b      = (const float*)d_in[5];
  const float* ln2_g      = (const float*)d_in[6];
  const float* ln2_b      = (const float*)d_in[7];
  const float* ffn_theta  = (const float*)d_in[8];
  const float* ffn_W1     = (const float*)d_in[9];
  const float* ffn_b1     = (const float*)d_in[10];
  const float* ffn_W2     = (const float*)d_in[11];
  const float* ffn_b2     = (const float*)d_in[12];
  const float* enc_W1 = (const float*)d_in[13]; const float* enc_b1 = (const float*)d_in[14];
  const float* enc_W2 = (const float*)d_in[15]; const float* enc_b2 = (const float*)d_in[16];
  const float* enc_W3 = (const float*)d_in[17]; const float* enc_b3 = (const float*)d_in[18];
  const float* dec_W1 = (const float*)d_in[19]; const float* dec_b1 = (const float*)d_in[20];
  const float* dec_W2 = (const float*)d_in[21]; const float* dec_b2 = (const float*)d_in[22];
  const float* dec_W3 = (const float*)d_in[23]; const float* dec_b3 = (const float*)d_in[24];
  const float* cls_W  = (const float*)d_in[25]; const float* cls_b  = (const float*)d_in[26];

  float* x       = (float*)d_ws;                      // 1M floats
  float* o_out   = x + (size_t)TOKENS * 64;           // 1M floats
  float* ps_out  = o_out + (size_t)TOKENS * 64;       // 128K floats
  float* partial = ps_out + (size_t)TOKENS * 8;       // 64K floats
  float* out     = (float*)d_out;

  embed_kernel<<<(TOKENS * 32 + 255) / 256, 256, 0, stream>>>(tokens, emb, x);
  for (int l = 0; l < 2; ++l) {
    attn_kernel<<<128 * 8, 256, 0, stream>>>(x, attn_theta + l * 8, o_out, ps_out);
    tail1_kernel<<<TOKENS / 16, 256, 0, stream>>>(
        x, o_out, ps_out, combine_W + l * 4096, ln1_g + l * 64, ln1_b + l * 64);
    tail2_kernel<<<TOKENS / 16, 256, 0, stream>>>(
        x, ln2_g + l * 64, ln2_b + l * 64,
        ffn_theta + l * 8, ffn_W1 + l * 1024, ffn_b1 + l * 128,
        ffn_W2 + l * 8192, ffn_b2 + l * 64, partial, (l == 1) ? 1 : 0);
  }
  head_kernel<<<16, 128, 0, stream>>>(partial, enc_W1, enc_b1, enc_W2, enc_b2,
                                      enc_W3, enc_b3, dec_W1, dec_b1, dec_W2,
                                      dec_b2, dec_W3, dec_b3, cls_W, cls_b, out);
}